// Round 3
// baseline (153.627 us; speedup 1.0000x reference)
//
#include <hip/hip_runtime.h>

// Problem constants (match reference)
#define NB 8
#define HH 352
#define WW 352
#define RAD 5
#define TX 32
#define TY 16
#define LW (TX + 2*RAD)     // 42
#define LH (TY + 2*RAD)     // 26
#define LSTRIDE 43          // padded row stride in float4 units (odd -> spread banks)
#define TILES_X (WW / TX)   // 11
#define TILES_Y (HH / TY)   // 22
#define NBLK (TILES_X * TILES_Y * NB)  // 1936

// Pre-scale rgb by sqrt(ALPHA * log2(e)) so wgt = exp2(-sum(d^2)):
// sqrt(200 * 1.4426950408889634)
#define RGB_SCALE 16.98644781888824f

__device__ __forceinline__ void bilateral_tap(const float4& wn, const float4& c,
                                              float& acc) {
    float d0 = wn.x - c.x, d1 = wn.y - c.y, d2 = wn.z - c.z;
    float s = fmaf(d0, d0, fmaf(d1, d1, d2 * d2));
    float e = __builtin_amdgcn_exp2f(-s);   // raw v_exp_f32, no OCML fixup
    acc = fmaf(e, fabsf(wn.w - c.w), acc);
}

template <bool INTERIOR>
__device__ __forceinline__ void mask_and_accum(const float4* tile, int ty, int px0,
                                               int gy, int gx0,
                                               float acc0, float acc1,
                                               float& num, float& den) {
    float accs[2] = {acc0, acc1};
    #pragma unroll
    for (int k = 0; k < 2; ++k) {
        int px = px0 + k;
        float mn = 1.f, mx = 0.f;
        #pragma unroll
        for (int dy2 = -2; dy2 <= 2; ++dy2) {
            bool rowv = INTERIOR || ((unsigned)(gy + dy2) < (unsigned)HH);
            #pragma unroll
            for (int dx2 = -2; dx2 <= 2; ++dx2) {
                float sal = tile[(ty + RAD + dy2) * LSTRIDE + (px + RAD + dx2)].w;
                float l = (sal > 0.5f) ? 1.f : 0.f;
                if (INTERIOR) {
                    mx = fmaxf(mx, l);
                    mn = fminf(mn, l);
                } else {
                    bool valid = rowv && ((unsigned)(gx0 + k + dx2) < (unsigned)WW);
                    mx = fmaxf(mx, l);               // OOB LDS sal==0 -> neutral for max
                    mn = fminf(mn, valid ? l : 1.f); // OOB excluded from min
                }
            }
        }
        float mask = mx - mn;  // 0 or 1
        num = fmaf(mask, accs[k], num);
        den += mask;
    }
}

__global__ __launch_bounds__(256, 4)
void btm_loss_kernel(const float* __restrict__ pred,
                     const float* __restrict__ feat,
                     float* __restrict__ ws,     // [num, den, counter]
                     float* __restrict__ out) {
    __shared__ float4 tile[LH * LSTRIDE];  // 26*43*16B = 17.9 KB
    __shared__ float2 wred[4];

    int bid = blockIdx.x;
    int tx_blk = bid % TILES_X;
    int ty_blk = (bid / TILES_X) % TILES_Y;
    int n = bid / (TILES_X * TILES_Y);

    const int x0 = tx_blk * TX;
    const int y0 = ty_blk * TY;

    const size_t plane = (size_t)HH * WW;
    const float* fr = feat + ((size_t)n * 3 + 0) * plane;
    const float* fg = feat + ((size_t)n * 3 + 1) * plane;
    const float* fb = feat + ((size_t)n * 3 + 2) * plane;
    const float* ps = pred + (size_t)n * plane;

    // ---- stage tile (zero-padded halo, matching jnp.pad; rgb pre-scaled) ----
    for (int i = threadIdx.x; i < LH * LW; i += 256) {
        int lr = i / LW;
        int lc = i - lr * LW;
        int gy = y0 + lr - RAD;
        int gx = x0 + lc - RAD;
        float4 v = make_float4(0.f, 0.f, 0.f, 0.f);
        if ((unsigned)gy < (unsigned)HH && (unsigned)gx < (unsigned)WW) {
            int gi = gy * WW + gx;
            v.x = fr[gi] * RGB_SCALE;
            v.y = fg[gi] * RGB_SCALE;
            v.z = fb[gi] * RGB_SCALE;
            v.w = ps[gi];
        }
        tile[lr * LSTRIDE + lc] = v;
    }
    __syncthreads();

    const int t   = threadIdx.x;
    const int txq = t & 15;   // 0..15 (x group)
    const int ty  = t >> 4;   // 0..15 (row)
    const int px0 = txq * 2;  // local x of first of 2 pixels

    float4 c0 = tile[(ty + RAD) * LSTRIDE + (px0 + 0 + RAD)];
    float4 c1 = tile[(ty + RAD) * LSTRIDE + (px0 + 1 + RAD)];

    float acc0 = 0.f, acc1 = 0.f;

    // ---- 11x11 bilateral accumulation, register-rolled over x ----
    for (int dy = 0; dy < 11; ++dy) {
        const float4* row = &tile[(ty + dy) * LSTRIDE + px0];
        float4 wv[12];
        #pragma unroll
        for (int j = 0; j < 12; ++j) wv[j] = row[j];

        #pragma unroll
        for (int dx = 0; dx < 11; ++dx) {
            bilateral_tap(wv[dx + 0], c0, acc0);
            bilateral_tap(wv[dx + 1], c1, acc1);
        }
    }

    // ---- mask (dil - ero of 5x5 maxpool on lbl; OOB taps excluded) ----
    const int gy = y0 + ty;
    const int gx0 = x0 + px0;
    float num = 0.f, den = 0.f;
    bool interior = (tx_blk >= 1) && (tx_blk <= 9) && (ty_blk >= 1) && (ty_blk <= 20);
    if (interior)
        mask_and_accum<true>(tile, ty, px0, gy, gx0, acc0, acc1, num, den);
    else
        mask_and_accum<false>(tile, ty, px0, gy, gx0, acc0, acc1, num, den);

    // ---- wave reduce -> block reduce -> global atomic; last block finalizes ----
    #pragma unroll
    for (int off = 32; off > 0; off >>= 1) {
        num += __shfl_down(num, off, 64);
        den += __shfl_down(den, off, 64);
    }
    int wid  = t >> 6;
    int lane = t & 63;
    if (lane == 0) wred[wid] = make_float2(num, den);
    __syncthreads();
    if (t == 0) {
        float2 a = wred[0];
        #pragma unroll
        for (int w = 1; w < 4; ++w) { a.x += wred[w].x; a.y += wred[w].y; }
        atomicAdd(&ws[0], a.x);
        atomicAdd(&ws[1], a.y);
        __threadfence();
        unsigned old = atomicAdd((unsigned*)&ws[2], 1u);
        if (old == (unsigned)(NBLK - 1)) {
            // last block: read totals via atomic (device-scope, sees all adds)
            float nsum = atomicAdd(&ws[0], 0.0f);
            float dsum = atomicAdd(&ws[1], 0.0f);
            out[0] = nsum / (dsum + 1e-6f);
        }
    }
}

extern "C" void kernel_launch(void* const* d_in, const int* in_sizes, int n_in,
                              void* d_out, int out_size, void* d_ws, size_t ws_size,
                              hipStream_t stream) {
    const float* pred = (const float*)d_in[0];  // (8,1,352,352) fp32
    const float* feat = (const float*)d_in[1];  // (8,3,352,352) fp32
    float* out = (float*)d_out;                 // scalar fp32
    float* ws  = (float*)d_ws;

    // zero [num, den, counter] (ws is re-poisoned to 0xAA before every call)
    hipMemsetAsync(d_ws, 0, 3 * sizeof(float), stream);

    btm_loss_kernel<<<dim3(NBLK), dim3(256), 0, stream>>>(pred, feat, ws, out);
}

// Round 4
// 106.764 us; speedup vs baseline: 1.4389x; 1.4389x over previous
//
#include <hip/hip_runtime.h>

// Problem constants (match reference)
#define NB 8
#define HH 352
#define WW 352
#define RAD 5
#define TX 32
#define TY 16
#define LW (TX + 2*RAD)     // 42
#define LH (TY + 2*RAD)     // 26
#define LSTRIDE 43          // padded row stride in float4 units (odd -> spread banks)
#define TILES_X (WW / TX)   // 11
#define TILES_Y (HH / TY)   // 22
#define NBLK (TILES_X * TILES_Y * NB)  // 1936

// Pre-scale rgb by sqrt(ALPHA * log2(e)) so wgt = exp2(-sum(d^2)):
// sqrt(200 * 1.4426950408889634)
#define RGB_SCALE 16.98644781888824f

__device__ __forceinline__ void bilateral_tap(const float4& wn, const float4& c,
                                              float& acc) {
    float d0 = wn.x - c.x, d1 = wn.y - c.y, d2 = wn.z - c.z;
    float s = fmaf(d0, d0, fmaf(d1, d1, d2 * d2));
    float e = __builtin_amdgcn_exp2f(-s);   // raw v_exp_f32, no OCML fixup
    acc = fmaf(e, fabsf(wn.w - c.w), acc);
}

// Separable 5x5 dil-ero mask for 4 x-adjacent pixels (column min/max first,
// then 5-wide horizontal window). OOB rows/cols: excluded from min (feed 1),
// neutral 0 for max (tile halo sal==0 -> lbl==0).
template <bool INTERIOR>
__device__ __forceinline__ void compute_mask4(const float4* __restrict__ tile,
                                              int ty, int px0, int gy, int gx0,
                                              float* mask) {
    float cmx[8], cmn[8];
    #pragma unroll
    for (int j = 0; j < 8; ++j) {
        int col = px0 + 3 + j;  // tile x of (gx0 - 2 + j)
        float mx = 0.f, mn = 1.f;
        #pragma unroll
        for (int r = 0; r < 5; ++r) {
            float l = (tile[(ty + 3 + r) * LSTRIDE + col].w > 0.5f) ? 1.f : 0.f;
            mx = fmaxf(mx, l);
            if (INTERIOR) {
                mn = fminf(mn, l);
            } else {
                bool rowv = (unsigned)(gy - 2 + r) < (unsigned)HH;
                mn = fminf(mn, rowv ? l : 1.f);
            }
        }
        cmx[j] = mx;
        if (INTERIOR) {
            cmn[j] = mn;
        } else {
            bool colv = (unsigned)(gx0 - 2 + j) < (unsigned)WW;
            cmn[j] = colv ? mn : 1.f;
        }
    }
    #pragma unroll
    for (int k = 0; k < 4; ++k) {
        float mx = cmx[k], mn = cmn[k];
        #pragma unroll
        for (int j2 = 1; j2 < 5; ++j2) {
            mx = fmaxf(mx, cmx[k + j2]);
            mn = fminf(mn, cmn[k + j2]);
        }
        mask[k] = mx - mn;  // 0 or 1
    }
}

__global__ __launch_bounds__(256, 4)
void btm_loss_kernel(const float* __restrict__ pred,
                     const float* __restrict__ feat,
                     float2* __restrict__ partials) {
    __shared__ float4 tile[LH * LSTRIDE];  // 26*43*16B = 17.9 KB
    __shared__ float4 xch[128];            // dy-split partial-acc exchange
    __shared__ float2 wred[4];

    int bid = blockIdx.x;
    int tx_blk = bid % TILES_X;
    int ty_blk = (bid / TILES_X) % TILES_Y;
    int n = bid / (TILES_X * TILES_Y);

    const int x0 = tx_blk * TX;
    const int y0 = ty_blk * TY;

    const size_t plane = (size_t)HH * WW;
    const float* fr = feat + ((size_t)n * 3 + 0) * plane;
    const float* fg = feat + ((size_t)n * 3 + 1) * plane;
    const float* fb = feat + ((size_t)n * 3 + 2) * plane;
    const float* ps = pred + (size_t)n * plane;

    // ---- stage tile (zero-padded halo, matching jnp.pad; rgb pre-scaled) ----
    for (int i = threadIdx.x; i < LH * LW; i += 256) {
        int lr = i / LW;
        int lc = i - lr * LW;
        int gy = y0 + lr - RAD;
        int gx = x0 + lc - RAD;
        float4 v = make_float4(0.f, 0.f, 0.f, 0.f);
        if ((unsigned)gy < (unsigned)HH && (unsigned)gx < (unsigned)WW) {
            int gi = gy * WW + gx;
            v.x = fr[gi] * RGB_SCALE;
            v.y = fg[gi] * RGB_SCALE;
            v.z = fb[gi] * RGB_SCALE;
            v.w = ps[gi];
        }
        tile[lr * LSTRIDE + lc] = v;
    }
    __syncthreads();

    // thread mapping: 2 groups (wave-pairs) split the 11 dy rows; each thread
    // owns 4 x-adjacent pixels of the 32x16 tile.
    const int t   = threadIdx.x;
    const int g   = t >> 7;      // 0: dy 0..5, 1: dy 6..10 (wave-uniform)
    const int tl  = t & 127;
    const int txq = tl & 7;      // 0..7  (x group)
    const int ty  = tl >> 3;     // 0..15 (row)
    const int px0 = txq * 4;

    float4 c0 = tile[(ty + RAD) * LSTRIDE + (px0 + 0 + RAD)];
    float4 c1 = tile[(ty + RAD) * LSTRIDE + (px0 + 1 + RAD)];
    float4 c2 = tile[(ty + RAD) * LSTRIDE + (px0 + 2 + RAD)];
    float4 c3 = tile[(ty + RAD) * LSTRIDE + (px0 + 3 + RAD)];

    float acc0 = 0.f, acc1 = 0.f, acc2 = 0.f, acc3 = 0.f;

    // ---- 11x11 bilateral accumulation: each window element read once and
    // fed to the (up to) 4 taps it serves ----
    const int dy_lo = g ? 6 : 0;
    const int dy_hi = g ? 11 : 6;
    for (int dy = dy_lo; dy < dy_hi; ++dy) {
        const float4* row = &tile[(ty + dy) * LSTRIDE + px0];
        #pragma unroll
        for (int j = 0; j < 14; ++j) {
            float4 wn = row[j];
            if (j - 0 >= 0 && j - 0 <= 10) bilateral_tap(wn, c0, acc0);
            if (j - 1 >= 0 && j - 1 <= 10) bilateral_tap(wn, c1, acc1);
            if (j - 2 >= 0 && j - 2 <= 10) bilateral_tap(wn, c2, acc2);
            if (j - 3 >= 0 && j - 3 <= 10) bilateral_tap(wn, c3, acc3);
        }
    }

    // ---- exchange: group 1 hands its partial accs to group 0 ----
    if (g == 1) xch[tl] = make_float4(acc0, acc1, acc2, acc3);
    __syncthreads();

    float num = 0.f, den = 0.f;
    if (g == 0) {
        float4 o = xch[tl];
        acc0 += o.x; acc1 += o.y; acc2 += o.z; acc3 += o.w;

        const int gy  = y0 + ty;
        const int gx0 = x0 + px0;
        float mask[4];
        bool interior = (tx_blk >= 1) && (tx_blk <= 9) &&
                        (ty_blk >= 1) && (ty_blk <= 20);
        if (interior) compute_mask4<true >(tile, ty, px0, gy, gx0, mask);
        else          compute_mask4<false>(tile, ty, px0, gy, gx0, mask);

        num = fmaf(mask[0], acc0, fmaf(mask[1], acc1,
              fmaf(mask[2], acc2, mask[3] * acc3)));
        den = ((mask[0] + mask[1]) + (mask[2] + mask[3]));
    }

    // ---- wave reduce -> block reduce -> deterministic partial store ----
    #pragma unroll
    for (int off = 32; off > 0; off >>= 1) {
        num += __shfl_down(num, off, 64);
        den += __shfl_down(den, off, 64);
    }
    int wid  = t >> 6;
    int lane = t & 63;
    if (lane == 0) wred[wid] = make_float2(num, den);
    __syncthreads();
    if (t == 0) {
        float2 a = wred[0];
        a.x += wred[1].x; a.y += wred[1].y;  // waves 2,3 contribute zeros
        partials[bid] = a;
    }
}

__global__ __launch_bounds__(256)
void btm_finalize_kernel(const float2* __restrict__ partials,
                         float* __restrict__ out) {
    __shared__ float2 wred[4];
    float num = 0.f, den = 0.f;
    for (int i = threadIdx.x; i < NBLK; i += 256) {
        float2 p = partials[i];
        num += p.x;
        den += p.y;
    }
    #pragma unroll
    for (int off = 32; off > 0; off >>= 1) {
        num += __shfl_down(num, off, 64);
        den += __shfl_down(den, off, 64);
    }
    int wid  = threadIdx.x >> 6;
    int lane = threadIdx.x & 63;
    if (lane == 0) wred[wid] = make_float2(num, den);
    __syncthreads();
    if (threadIdx.x == 0) {
        float2 a = wred[0];
        #pragma unroll
        for (int w = 1; w < 4; ++w) { a.x += wred[w].x; a.y += wred[w].y; }
        out[0] = a.x / (a.y + 1e-6f);
    }
}

extern "C" void kernel_launch(void* const* d_in, const int* in_sizes, int n_in,
                              void* d_out, int out_size, void* d_ws, size_t ws_size,
                              hipStream_t stream) {
    const float* pred = (const float*)d_in[0];  // (8,1,352,352) fp32
    const float* feat = (const float*)d_in[1];  // (8,3,352,352) fp32
    float* out = (float*)d_out;                 // scalar fp32
    float2* partials = (float2*)d_ws;           // NBLK float2 = 15.5 KB

    btm_loss_kernel<<<dim3(NBLK), dim3(256), 0, stream>>>(pred, feat, partials);
    btm_finalize_kernel<<<dim3(1), dim3(256), 0, stream>>>(partials, out);
}

// Round 5
// 101.010 us; speedup vs baseline: 1.5209x; 1.0570x over previous
//
#include <hip/hip_runtime.h>

// Problem constants (match reference)
#define NB 8
#define HH 352
#define WW 352
#define RAD 5
#define TX 32
#define TY 16
#define LW (TX + 2*RAD)     // 42
#define LH (TY + 2*RAD)     // 26
#define LSTRIDE 43          // padded row stride in float4 units (odd -> spread banks)
#define TILES_X (WW / TX)   // 11
#define TILES_Y (HH / TY)   // 22
#define NBLK (TILES_X * TILES_Y * NB)  // 1936

// Pre-scale rgb by sqrt(ALPHA * log2(e)) so wgt = exp2(-sum(d^2)):
// sqrt(200 * 1.4426950408889634)
#define RGB_SCALE 16.98644781888824f

typedef float f32x2 __attribute__((ext_vector_type(2)));

// One window element vs a PAIR of centers — packed fp32 (v_pk_*) path.
__device__ __forceinline__ void tap_pair(float wx, float wy, float wz, float ww,
                                         f32x2 cx, f32x2 cy, f32x2 cz, f32x2 cw,
                                         float& accA, float& accB) {
    f32x2 d0 = cx - wx;          // pk_add (neg): sign irrelevant, squared next
    f32x2 d1 = cy - wy;
    f32x2 d2 = cz - wz;
    f32x2 s  = d0 * d0;
    s += d1 * d1;                // contract -> pk_fma
    s += d2 * d2;
    f32x2 ds = cw - ww;
    accA = fmaf(__builtin_amdgcn_exp2f(-s.x), fabsf(ds.x), accA);
    accB = fmaf(__builtin_amdgcn_exp2f(-s.y), fabsf(ds.y), accB);
}

__device__ __forceinline__ void tap_scalar(const float4& wn, const float4& c,
                                           float& acc) {
    float d0 = wn.x - c.x, d1 = wn.y - c.y, d2 = wn.z - c.z;
    float s = fmaf(d0, d0, fmaf(d1, d1, d2 * d2));
    float e = __builtin_amdgcn_exp2f(-s);   // raw v_exp_f32
    acc = fmaf(e, fabsf(wn.w - c.w), acc);
}

// Separable 5x5 dil-ero mask for 4 x-adjacent pixels.
template <bool INTERIOR>
__device__ __forceinline__ void compute_mask4(const float4* __restrict__ tile,
                                              int ty, int px0, int gy, int gx0,
                                              float* mask) {
    float cmx[8], cmn[8];
    #pragma unroll
    for (int j = 0; j < 8; ++j) {
        int col = px0 + 3 + j;  // tile x of (gx0 - 2 + j)
        float mx = 0.f, mn = 1.f;
        #pragma unroll
        for (int r = 0; r < 5; ++r) {
            float l = (tile[(ty + 3 + r) * LSTRIDE + col].w > 0.5f) ? 1.f : 0.f;
            mx = fmaxf(mx, l);
            if (INTERIOR) {
                mn = fminf(mn, l);
            } else {
                bool rowv = (unsigned)(gy - 2 + r) < (unsigned)HH;
                mn = fminf(mn, rowv ? l : 1.f);
            }
        }
        cmx[j] = mx;
        if (INTERIOR) {
            cmn[j] = mn;
        } else {
            bool colv = (unsigned)(gx0 - 2 + j) < (unsigned)WW;
            cmn[j] = colv ? mn : 1.f;
        }
    }
    #pragma unroll
    for (int k = 0; k < 4; ++k) {
        float mx = cmx[k], mn = cmn[k];
        #pragma unroll
        for (int j2 = 1; j2 < 5; ++j2) {
            mx = fmaxf(mx, cmx[k + j2]);
            mn = fminf(mn, cmn[k + j2]);
        }
        mask[k] = mx - mn;  // 0 or 1
    }
}

__global__ __launch_bounds__(256, 4)
void btm_loss_kernel(const float* __restrict__ pred,
                     const float* __restrict__ feat,
                     float2* __restrict__ partials) {
    __shared__ float4 tile[LH * LSTRIDE];  // 26*43*16B = 17.9 KB
    __shared__ float4 xch[128];            // dy-split partial-acc exchange
    __shared__ float2 wred[4];

    int bid = blockIdx.x;
    int tx_blk = bid % TILES_X;
    int ty_blk = (bid / TILES_X) % TILES_Y;
    int n = bid / (TILES_X * TILES_Y);

    const int x0 = tx_blk * TX;
    const int y0 = ty_blk * TY;

    const size_t plane = (size_t)HH * WW;
    const float* fr = feat + ((size_t)n * 3 + 0) * plane;
    const float* fg = feat + ((size_t)n * 3 + 1) * plane;
    const float* fb = feat + ((size_t)n * 3 + 2) * plane;
    const float* ps = pred + (size_t)n * plane;

    // ---- stage tile (zero-padded halo, matching jnp.pad; rgb pre-scaled) ----
    for (int i = threadIdx.x; i < LH * LW; i += 256) {
        int lr = i / LW;
        int lc = i - lr * LW;
        int gy = y0 + lr - RAD;
        int gx = x0 + lc - RAD;
        float4 v = make_float4(0.f, 0.f, 0.f, 0.f);
        if ((unsigned)gy < (unsigned)HH && (unsigned)gx < (unsigned)WW) {
            int gi = gy * WW + gx;
            v.x = fr[gi] * RGB_SCALE;
            v.y = fg[gi] * RGB_SCALE;
            v.z = fb[gi] * RGB_SCALE;
            v.w = ps[gi];
        }
        tile[lr * LSTRIDE + lc] = v;
    }
    __syncthreads();

    // 2 wave-pair groups split the 11 dy rows; each thread owns 4 x-adjacent px.
    const int t   = threadIdx.x;
    const int g   = t >> 7;      // 0: dy 0..5, 1: dy 6..10 (wave-uniform)
    const int tl  = t & 127;
    const int txq = tl & 7;      // 0..7  (x group)
    const int ty  = tl >> 3;     // 0..15 (row)
    const int px0 = txq * 4;

    float4 c0 = tile[(ty + RAD) * LSTRIDE + (px0 + 0 + RAD)];
    float4 c1 = tile[(ty + RAD) * LSTRIDE + (px0 + 1 + RAD)];
    float4 c2 = tile[(ty + RAD) * LSTRIDE + (px0 + 2 + RAD)];
    float4 c3 = tile[(ty + RAD) * LSTRIDE + (px0 + 3 + RAD)];

    // packed center pairs
    f32x2 c01x = {c0.x, c1.x}, c01y = {c0.y, c1.y}, c01z = {c0.z, c1.z}, c01w = {c0.w, c1.w};
    f32x2 c23x = {c2.x, c3.x}, c23y = {c2.y, c3.y}, c23z = {c2.z, c3.z}, c23w = {c2.w, c3.w};

    float acc0 = 0.f, acc1 = 0.f, acc2 = 0.f, acc3 = 0.f;

    const int dy_lo = g ? 6 : 0;
    const int dy_hi = g ? 11 : 6;
    for (int dy = dy_lo; dy < dy_hi; ++dy) {
        const float4* row = &tile[(ty + dy) * LSTRIDE + px0];
        float4 wv[14];
        #pragma unroll
        for (int j = 0; j < 14; ++j) wv[j] = row[j];

        // edge taps (pair halves with non-overlapping valid ranges)
        tap_scalar(wv[0],  c0, acc0);   // c0: dx=0
        tap_scalar(wv[11], c1, acc1);   // c1: dx=10
        tap_scalar(wv[2],  c2, acc2);   // c2: dx=0
        tap_scalar(wv[13], c3, acc3);   // c3: dx=10

        #pragma unroll
        for (int j = 1; j <= 10; ++j)
            tap_pair(wv[j].x, wv[j].y, wv[j].z, wv[j].w,
                     c01x, c01y, c01z, c01w, acc0, acc1);
        #pragma unroll
        for (int j = 3; j <= 12; ++j)
            tap_pair(wv[j].x, wv[j].y, wv[j].z, wv[j].w,
                     c23x, c23y, c23z, c23w, acc2, acc3);
    }

    // ---- exchange: group 1 hands its partial accs to group 0 ----
    if (g == 1) xch[tl] = make_float4(acc0, acc1, acc2, acc3);
    __syncthreads();

    float num = 0.f, den = 0.f;
    if (g == 0) {
        float4 o = xch[tl];
        acc0 += o.x; acc1 += o.y; acc2 += o.z; acc3 += o.w;

        const int gy  = y0 + ty;
        const int gx0 = x0 + px0;
        float mask[4];
        bool interior = (tx_blk >= 1) && (tx_blk <= 9) &&
                        (ty_blk >= 1) && (ty_blk <= 20);
        if (interior) compute_mask4<true >(tile, ty, px0, gy, gx0, mask);
        else          compute_mask4<false>(tile, ty, px0, gy, gx0, mask);

        num = fmaf(mask[0], acc0, fmaf(mask[1], acc1,
              fmaf(mask[2], acc2, mask[3] * acc3)));
        den = ((mask[0] + mask[1]) + (mask[2] + mask[3]));
    }

    // ---- wave reduce -> block reduce -> deterministic partial store ----
    #pragma unroll
    for (int off = 32; off > 0; off >>= 1) {
        num += __shfl_down(num, off, 64);
        den += __shfl_down(den, off, 64);
    }
    int wid  = t >> 6;
    int lane = t & 63;
    if (lane == 0) wred[wid] = make_float2(num, den);
    __syncthreads();
    if (t == 0) {
        float2 a = wred[0];
        a.x += wred[1].x; a.y += wred[1].y;  // waves 2,3 contribute zeros
        partials[bid] = a;
    }
}

__global__ __launch_bounds__(256)
void btm_finalize_kernel(const float2* __restrict__ partials,
                         float* __restrict__ out) {
    __shared__ float2 wred[4];
    float num = 0.f, den = 0.f;
    for (int i = threadIdx.x; i < NBLK; i += 256) {
        float2 p = partials[i];
        num += p.x;
        den += p.y;
    }
    #pragma unroll
    for (int off = 32; off > 0; off >>= 1) {
        num += __shfl_down(num, off, 64);
        den += __shfl_down(den, off, 64);
    }
    int wid  = threadIdx.x >> 6;
    int lane = threadIdx.x & 63;
    if (lane == 0) wred[wid] = make_float2(num, den);
    __syncthreads();
    if (threadIdx.x == 0) {
        float2 a = wred[0];
        #pragma unroll
        for (int w = 1; w < 4; ++w) { a.x += wred[w].x; a.y += wred[w].y; }
        out[0] = a.x / (a.y + 1e-6f);
    }
}

extern "C" void kernel_launch(void* const* d_in, const int* in_sizes, int n_in,
                              void* d_out, int out_size, void* d_ws, size_t ws_size,
                              hipStream_t stream) {
    const float* pred = (const float*)d_in[0];  // (8,1,352,352) fp32
    const float* feat = (const float*)d_in[1];  // (8,3,352,352) fp32
    float* out = (float*)d_out;                 // scalar fp32
    float2* partials = (float2*)d_ws;           // NBLK float2 = 15.5 KB

    btm_loss_kernel<<<dim3(NBLK), dim3(256), 0, stream>>>(pred, feat, partials);
    btm_finalize_kernel<<<dim3(1), dim3(256), 0, stream>>>(partials, out);
}